// Round 1
// baseline (202.764 us; speedup 1.0000x reference)
//
#include <hip/hip_runtime.h>
#include <math.h>

#define IMG_H 512
#define IMG_W 512
#define NIMG  16
#define HW    (IMG_H * IMG_W)

// Stage 1: compute channels 0..9 of the output from the 3-channel input.
// ch0=e0, ch1=e1, ch2=|e|, ch3=0.5*atan2(e0,e1), ch4=e0/|e|, ch5=e1/|e|,
// ch6=e0*e1, ch7=delta, ch8=max neighbor dot, ch9=min neighbor dot.
__global__ __launch_bounds__(256) void stage1_kernel(const float* __restrict__ x,
                                                     float* __restrict__ out) {
    int idx = blockIdx.x * blockDim.x + threadIdx.x;
    if (idx >= NIMG * HW) return;
    int n   = idx / HW;
    int rem = idx - n * HW;
    int h   = rem / IMG_W;
    int w   = rem - h * IMG_W;

    const float* xb = x + (size_t)n * 3 * HW;
    float e0 = xb[rem];
    float e1 = xb[HW + rem];
    float dl = xb[2 * HW + rem];

    float m   = sqrtf(e0 * e0 + e1 * e1);
    float ang = 0.5f * atan2f(e0, e1);
    float inv = 1.0f / m;
    float en0 = e0 * inv, en1 = e1 * inv;
    float cp  = e0 * e1;

    // Neighbor dot products of e_norm with zero padding semantics:
    // order (up = h+1, down = h-1, left = w+1, right = w-1); OOB -> 0.
    float dpu = 0.f, dpd = 0.f, dpl = 0.f, dpr = 0.f;
    if (h + 1 < IMG_H) {
        float a0 = xb[rem + IMG_W], a1 = xb[HW + rem + IMG_W];
        float mi = 1.0f / sqrtf(a0 * a0 + a1 * a1);
        dpu = en0 * (a0 * mi) + en1 * (a1 * mi);
    }
    if (h > 0) {
        float a0 = xb[rem - IMG_W], a1 = xb[HW + rem - IMG_W];
        float mi = 1.0f / sqrtf(a0 * a0 + a1 * a1);
        dpd = en0 * (a0 * mi) + en1 * (a1 * mi);
    }
    if (w + 1 < IMG_W) {
        float a0 = xb[rem + 1], a1 = xb[HW + rem + 1];
        float mi = 1.0f / sqrtf(a0 * a0 + a1 * a1);
        dpl = en0 * (a0 * mi) + en1 * (a1 * mi);
    }
    if (w > 0) {
        float a0 = xb[rem - 1], a1 = xb[HW + rem - 1];
        float mi = 1.0f / sqrtf(a0 * a0 + a1 * a1);
        dpr = en0 * (a0 * mi) + en1 * (a1 * mi);
    }
    float smax = fmaxf(fmaxf(dpu, dpd), fmaxf(dpl, dpr));
    float smin = fminf(fminf(dpu, dpd), fminf(dpl, dpr));

    float* ob = out + (size_t)n * 20 * HW + rem;
    ob[0]       = e0;
    ob[HW]      = e1;
    ob[2 * HW]  = m;
    ob[3 * HW]  = ang;
    ob[4 * HW]  = en0;
    ob[5 * HW]  = en1;
    ob[6 * HW]  = cp;
    ob[7 * HW]  = dl;
    ob[8 * HW]  = smax;
    ob[9 * HW]  = smin;
}

// Stage 2: depthwise 3x3 Sobel magnitude (zero padding) on channels 0..9,
// writing channels 10..19.
__global__ __launch_bounds__(256) void stage2_kernel(const float* __restrict__ outbuf,
                                                     float* __restrict__ out) {
    int idx = blockIdx.x * blockDim.x + threadIdx.x;
    if (idx >= NIMG * 10 * HW) return;
    int plane = idx / HW;        // n*10 + c
    int rem   = idx - plane * HW;
    int h     = rem / IMG_W;
    int w     = rem - h * IMG_W;
    int n     = plane / 10;
    int c     = plane - n * 10;

    const float* p = outbuf + ((size_t)n * 20 + c) * HW;

    float v[3][3];
#pragma unroll
    for (int a = 0; a < 3; ++a) {
#pragma unroll
        for (int b = 0; b < 3; ++b) {
            int hh = h + a - 1;
            int ww = w + b - 1;
            v[a][b] = (hh >= 0 && hh < IMG_H && ww >= 0 && ww < IMG_W)
                          ? p[hh * IMG_W + ww]
                          : 0.0f;
        }
    }
    float gx = (v[0][2] - v[0][0]) + 2.0f * (v[1][2] - v[1][0]) + (v[2][2] - v[2][0]);
    float gy = (v[2][0] + 2.0f * v[2][1] + v[2][2]) - (v[0][0] + 2.0f * v[0][1] + v[0][2]);

    out[((size_t)n * 20 + 10 + c) * HW + rem] = sqrtf(gx * gx + gy * gy);
}

extern "C" void kernel_launch(void* const* d_in, const int* in_sizes, int n_in,
                              void* d_out, int out_size, void* d_ws, size_t ws_size,
                              hipStream_t stream) {
    const float* x = (const float*)d_in[0];
    float* out = (float*)d_out;

    {
        int total = NIMG * HW;
        int block = 256;
        int grid  = (total + block - 1) / block;
        stage1_kernel<<<grid, block, 0, stream>>>(x, out);
    }
    {
        int total = NIMG * 10 * HW;
        int block = 256;
        int grid  = (total + block - 1) / block;
        stage2_kernel<<<grid, block, 0, stream>>>(out, out);
    }
}

// Round 2
// 135.407 us; speedup vs baseline: 1.4974x; 1.4974x over previous
//
#include <hip/hip_runtime.h>
#include <math.h>

#define IMG_H 512
#define IMG_W 512
#define NIMG  16
#define HW    (IMG_H * IMG_W)

// Tile geometry: 16 rows x 64 cols per block, halo of 1 on each side.
#define TH 16
#define TW 64
#define HTH (TH + 2)
#define HTW (TW + 2)
#define TILES_H (IMG_H / TH)   // 32
#define TILES_W (IMG_W / TW)   // 8

// Fused kernel: per tile, compute channels 0..9 on the (TH+2)x(TW+2) halo
// into LDS, then Sobel-magnitude from LDS for channels 10..19, writing all
// 20 output channels. Zero padding at image borders is represented by
// zeroed LDS halo cells (matches conv zero-padding AND e_norm zero-padding
// in the neighbor-similarity step).
__global__ __launch_bounds__(256) void fused_kernel(const float* __restrict__ x,
                                                    float* __restrict__ out) {
    __shared__ float lds[10][HTH * HTW];   // 10 * 18 * 66 * 4 = 47520 B

    int bid = blockIdx.x;
    int n   = bid / (TILES_H * TILES_W);
    int t   = bid - n * (TILES_H * TILES_W);
    int th  = t / TILES_W;
    int tw  = t - th * TILES_W;
    int h0  = th * TH;
    int w0  = tw * TW;

    const float* xb = x + (size_t)n * 3 * HW;
    int tid = threadIdx.x;

    // ---- Phase A: fill LDS with ch0..9 over the halo region ----
    for (int i = tid; i < HTH * HTW; i += 256) {
        int hr = i / HTW;
        int wc = i - hr * HTW;
        int h  = h0 + hr - 1;
        int w  = w0 + wc - 1;

        float e0 = 0.f, e1 = 0.f, m = 0.f, ang = 0.f, en0 = 0.f, en1 = 0.f;
        float cp = 0.f, dl = 0.f, smax = 0.f, smin = 0.f;

        if (h >= 0 && h < IMG_H && w >= 0 && w < IMG_W) {
            int rem = h * IMG_W + w;
            e0 = xb[rem];
            e1 = xb[HW + rem];
            dl = xb[2 * HW + rem];

            m   = sqrtf(e0 * e0 + e1 * e1);
            ang = 0.5f * atan2f(e0, e1);
            float inv = 1.0f / m;
            en0 = e0 * inv;
            en1 = e1 * inv;
            cp  = e0 * e1;

            float dpu = 0.f, dpd = 0.f, dpl = 0.f, dpr = 0.f;
            if (h + 1 < IMG_H) {
                float a0 = xb[rem + IMG_W], a1 = xb[HW + rem + IMG_W];
                float mi = 1.0f / sqrtf(a0 * a0 + a1 * a1);
                dpu = en0 * (a0 * mi) + en1 * (a1 * mi);
            }
            if (h > 0) {
                float a0 = xb[rem - IMG_W], a1 = xb[HW + rem - IMG_W];
                float mi = 1.0f / sqrtf(a0 * a0 + a1 * a1);
                dpd = en0 * (a0 * mi) + en1 * (a1 * mi);
            }
            if (w + 1 < IMG_W) {
                float a0 = xb[rem + 1], a1 = xb[HW + rem + 1];
                float mi = 1.0f / sqrtf(a0 * a0 + a1 * a1);
                dpl = en0 * (a0 * mi) + en1 * (a1 * mi);
            }
            if (w > 0) {
                float a0 = xb[rem - 1], a1 = xb[HW + rem - 1];
                float mi = 1.0f / sqrtf(a0 * a0 + a1 * a1);
                dpr = en0 * (a0 * mi) + en1 * (a1 * mi);
            }
            smax = fmaxf(fmaxf(dpu, dpd), fmaxf(dpl, dpr));
            smin = fminf(fminf(dpu, dpd), fminf(dpl, dpr));
        }

        lds[0][i] = e0;
        lds[1][i] = e1;
        lds[2][i] = m;
        lds[3][i] = ang;
        lds[4][i] = en0;
        lds[5][i] = en1;
        lds[6][i] = cp;
        lds[7][i] = dl;
        lds[8][i] = smax;
        lds[9][i] = smin;
    }

    __syncthreads();

    // ---- Phase B: write ch0..9 (copies) and ch10..19 (Sobel magnitude) ----
    // 1024 pixels / block handled as 512 float2 pairs; 256 threads x 2 iters.
    float* ob = out + (size_t)n * 20 * HW;

#pragma unroll
    for (int j = 0; j < (TH * TW) / (2 * 256); ++j) {
        int q = j * 256 + tid;          // pair index 0..511
        int r = q / (TW / 2);           // tile row 0..15
        int c = q - r * (TW / 2);       // pair col 0..31
        int h    = h0 + r;
        int wabs = w0 + 2 * c;
        int rem  = h * IMG_W + wabs;

        int base = (r + 1) * HTW + (2 * c + 1);  // LDS index of pixel0

#pragma unroll
        for (int ch = 0; ch < 10; ++ch) {
            const float* L = lds[ch];
            // window cols 2c .. 2c+3 (LDS indices base-1 .. base+2), rows r..r+2
            float t0 = L[base - HTW - 1], t1 = L[base - HTW], t2 = L[base - HTW + 1], t3 = L[base - HTW + 2];
            float m0 = L[base - 1],       m1 = L[base],       m2 = L[base + 1],       m3 = L[base + 2];
            float b0 = L[base + HTW - 1], b1 = L[base + HTW], b2 = L[base + HTW + 1], b3 = L[base + HTW + 2];

            float gx0 = (t2 - t0) + 2.0f * (m2 - m0) + (b2 - b0);
            float gy0 = (b0 + 2.0f * b1 + b2) - (t0 + 2.0f * t1 + t2);
            float gx1 = (t3 - t1) + 2.0f * (m3 - m1) + (b3 - b1);
            float gy1 = (b1 + 2.0f * b2 + b3) - (t1 + 2.0f * t2 + t3);

            float2 cen = make_float2(m1, m2);
            float2 mag = make_float2(sqrtf(gx0 * gx0 + gy0 * gy0),
                                     sqrtf(gx1 * gx1 + gy1 * gy1));

            *reinterpret_cast<float2*>(&ob[(size_t)ch * HW + rem])        = cen;
            *reinterpret_cast<float2*>(&ob[(size_t)(10 + ch) * HW + rem]) = mag;
        }
    }
}

extern "C" void kernel_launch(void* const* d_in, const int* in_sizes, int n_in,
                              void* d_out, int out_size, void* d_ws, size_t ws_size,
                              hipStream_t stream) {
    const float* x = (const float*)d_in[0];
    float* out = (float*)d_out;

    int grid = NIMG * TILES_H * TILES_W;   // 4096 blocks
    fused_kernel<<<grid, 256, 0, stream>>>(x, out);
}

// Round 3
// 124.054 us; speedup vs baseline: 1.6345x; 1.0915x over previous
//
#include <hip/hip_runtime.h>
#include <math.h>

#define IMG_H 512
#define IMG_W 512
#define NIMG  16
#define HW    (IMG_H * IMG_W)

#define TH 16
#define TW 64
#define HTH (TH + 2)          // 18 halo rows
#define HTW (TW + 2)          // 66 halo cols
#define LP  72                // padded LDS row stride (floats); left pad 3 for 16B alignment
#define TILES_H (IMG_H / TH)  // 32
#define TILES_W (IMG_W / TW)  // 8

__device__ __forceinline__ float rcp_fast(float v) {
#if __has_builtin(__builtin_amdgcn_rcpf)
    return __builtin_amdgcn_rcpf(v);
#else
    return 1.0f / v;
#endif
}
__device__ __forceinline__ float rsq_fast(float v) {
#if __has_builtin(__builtin_amdgcn_rsqf)
    return __builtin_amdgcn_rsqf(v);
#else
    return rsqrtf(v);
#endif
}
__device__ __forceinline__ float sqrt_fast(float v) {
#if __has_builtin(__builtin_amdgcn_sqrtf)
    return __builtin_amdgcn_sqrtf(v);
#else
    return sqrtf(v);
#endif
}

// atan2 via A&S-style polynomial; |err| ~1e-4 rad (abs threshold is 0.66).
__device__ __forceinline__ float fast_atan2f(float y, float x) {
    float ay = fabsf(y), ax = fabsf(x);
    float mx = fmaxf(ay, ax), mn = fminf(ay, ax);
    float a = mn * rcp_fast(mx);
    float s = a * a;
    float r = fmaf(fmaf(fmaf(0.0208351f, s, -0.085133f), s, 0.180141f), s, -0.3302995f);
    r = a * fmaf(r, s, 0.9998660f);
    if (ay > ax)  r = 1.57079632679f - r;
    if (x < 0.0f) r = 3.14159265359f - r;
    return copysignf(r, y);
}

__global__ __launch_bounds__(256, 3) void fused_kernel(const float* __restrict__ x,
                                                       float* __restrict__ out) {
    __shared__ __align__(16) float lds[10][HTH * LP];   // 10*18*72*4 = 51840 B -> 3 blocks/CU

    int bid = blockIdx.x;
    int n   = bid / (TILES_H * TILES_W);
    int t   = bid - n * (TILES_H * TILES_W);
    int th  = t / TILES_W;
    int tw  = t - th * TILES_W;
    int h0  = th * TH;
    int w0  = tw * TW;

    const float* xb = x + (size_t)n * 3 * HW;
    int tid = threadIdx.x;

    // ---- Phase A: ch0..9 over the (18 x 66) halo region into LDS ----
    for (int i = tid; i < HTH * HTW; i += 256) {
        int hr = i / HTW;
        int wc = i - hr * HTW;
        int h  = h0 + hr - 1;
        int w  = w0 + wc - 1;

        float e0 = 0.f, e1 = 0.f, m = 0.f, ang = 0.f, en0 = 0.f, en1 = 0.f;
        float cp = 0.f, dl = 0.f, smax = 0.f, smin = 0.f;

        if (h >= 0 && h < IMG_H && w >= 0 && w < IMG_W) {
            int rem = h * IMG_W + w;
            e0 = xb[rem];
            e1 = xb[HW + rem];
            dl = xb[2 * HW + rem];

            float s2 = fmaf(e0, e0, e1 * e1);
            m   = sqrt_fast(s2);
            float is = rsq_fast(s2);
            en0 = e0 * is;
            en1 = e1 * is;
            ang = 0.5f * fast_atan2f(e0, e1);
            cp  = e0 * e1;

            float dpu = 0.f, dpd = 0.f, dpl = 0.f, dpr = 0.f;
            if (h + 1 < IMG_H) {
                float a0 = xb[rem + IMG_W], a1 = xb[HW + rem + IMG_W];
                float mi = rsq_fast(fmaf(a0, a0, a1 * a1));
                dpu = fmaf(en0, a0 * mi, en1 * (a1 * mi));
            }
            if (h > 0) {
                float a0 = xb[rem - IMG_W], a1 = xb[HW + rem - IMG_W];
                float mi = rsq_fast(fmaf(a0, a0, a1 * a1));
                dpd = fmaf(en0, a0 * mi, en1 * (a1 * mi));
            }
            if (w + 1 < IMG_W) {
                float a0 = xb[rem + 1], a1 = xb[HW + rem + 1];
                float mi = rsq_fast(fmaf(a0, a0, a1 * a1));
                dpl = fmaf(en0, a0 * mi, en1 * (a1 * mi));
            }
            if (w > 0) {
                float a0 = xb[rem - 1], a1 = xb[HW + rem - 1];
                float mi = rsq_fast(fmaf(a0, a0, a1 * a1));
                dpr = fmaf(en0, a0 * mi, en1 * (a1 * mi));
            }
            smax = fmaxf(fmaxf(dpu, dpd), fmaxf(dpl, dpr));
            smin = fminf(fminf(dpu, dpd), fminf(dpl, dpr));
        }

        int li = hr * LP + wc + 3;   // +3 left pad so interior col 4c is 16B-aligned
        lds[0][li] = e0;
        lds[1][li] = e1;
        lds[2][li] = m;
        lds[3][li] = ang;
        lds[4][li] = en0;
        lds[5][li] = en1;
        lds[6][li] = cp;
        lds[7][li] = dl;
        lds[8][li] = smax;
        lds[9][li] = smin;
    }

    __syncthreads();

    // ---- Phase B: each thread owns 4 consecutive pixels of one row ----
    int r  = tid >> 4;          // 0..15
    int c  = tid & 15;          // 0..15 -> cols 4c..4c+3
    int h  = h0 + r;
    int wa = w0 + 4 * c;
    float* op = out + (size_t)n * 20 * HW + (size_t)h * IMG_W + wa;
    int lb = (r + 1) * LP + 4 * c + 4;   // LDS idx of tile col 4c, middle row

#pragma unroll
    for (int ch = 0; ch < 10; ++ch) {
        const float* L = lds[ch];

        float4 tq = *reinterpret_cast<const float4*>(&L[lb - LP]);
        float  tl = L[lb - LP - 1], tr = L[lb - LP + 4];
        float4 mq = *reinterpret_cast<const float4*>(&L[lb]);
        float  ml = L[lb - 1],      mr = L[lb + 4];
        float4 bq = *reinterpret_cast<const float4*>(&L[lb + LP]);
        float  bl = L[lb + LP - 1], br = L[lb + LP + 4];

        float tt[6] = {tl, tq.x, tq.y, tq.z, tq.w, tr};
        float mm[6] = {ml, mq.x, mq.y, mq.z, mq.w, mr};
        float bb[6] = {bl, bq.x, bq.y, bq.z, bq.w, br};

        float vs[6], dd[6];
#pragma unroll
        for (int j = 0; j < 6; ++j) {
            vs[j] = tt[j] + fmaf(2.0f, mm[j], bb[j]);   // vertical [1,2,1] for gx
            dd[j] = bb[j] - tt[j];                       // vertical [-1,0,1] for gy
        }

        float4 mag;
        float gx, gy;
        gx = vs[2] - vs[0]; gy = fmaf(2.0f, dd[1], dd[0] + dd[2]);
        mag.x = sqrt_fast(fmaf(gx, gx, gy * gy));
        gx = vs[3] - vs[1]; gy = fmaf(2.0f, dd[2], dd[1] + dd[3]);
        mag.y = sqrt_fast(fmaf(gx, gx, gy * gy));
        gx = vs[4] - vs[2]; gy = fmaf(2.0f, dd[3], dd[2] + dd[4]);
        mag.z = sqrt_fast(fmaf(gx, gx, gy * gy));
        gx = vs[5] - vs[3]; gy = fmaf(2.0f, dd[4], dd[3] + dd[5]);
        mag.w = sqrt_fast(fmaf(gx, gx, gy * gy));

        *reinterpret_cast<float4*>(&op[(size_t)ch * HW])        = mq;
        *reinterpret_cast<float4*>(&op[(size_t)(10 + ch) * HW]) = mag;
    }
}

extern "C" void kernel_launch(void* const* d_in, const int* in_sizes, int n_in,
                              void* d_out, int out_size, void* d_ws, size_t ws_size,
                              hipStream_t stream) {
    const float* x = (const float*)d_in[0];
    float* out = (float*)d_out;

    int grid = NIMG * TILES_H * TILES_W;   // 4096
    fused_kernel<<<grid, 256, 0, stream>>>(x, out);
}

// Round 5
// 74.720 us; speedup vs baseline: 2.7136x; 1.6602x over previous
//
#include <hip/hip_runtime.h>
#include <hip/hip_fp16.h>
#include <math.h>

#define IMG_H 512
#define IMG_W 512
#define NIMG  16
#define HW    (IMG_H * IMG_W)

#define TH 16
#define TW 64
#define HTH (TH + 2)          // 18 halo rows
#define HTW (TW + 2)          // 66 halo cols
#define LPH 72                // LDS row stride in halves (144 B, 8B-aligned)
#define PAD 4                 // left pad (halves) so b64 reads are 8B-aligned
#define TILES_H (IMG_H / TH)  // 32
#define TILES_W (IMG_W / TW)  // 8

typedef float vfloat4 __attribute__((ext_vector_type(4)));

__device__ __forceinline__ float rcp_fast(float v) {
#if __has_builtin(__builtin_amdgcn_rcpf)
    return __builtin_amdgcn_rcpf(v);
#else
    return 1.0f / v;
#endif
}
__device__ __forceinline__ float rsq_fast(float v) {
#if __has_builtin(__builtin_amdgcn_rsqf)
    return __builtin_amdgcn_rsqf(v);
#else
    return rsqrtf(v);
#endif
}
__device__ __forceinline__ float sqrt_fast(float v) {
#if __has_builtin(__builtin_amdgcn_sqrtf)
    return __builtin_amdgcn_sqrtf(v);
#else
    return sqrtf(v);
#endif
}

// atan2 via polynomial; |err| ~1e-4 rad (abs threshold is 0.66).
__device__ __forceinline__ float fast_atan2f(float y, float x) {
    float ay = fabsf(y), ax = fabsf(x);
    float mx = fmaxf(ay, ax), mn = fminf(ay, ax);
    float a = mn * rcp_fast(mx);
    float s = a * a;
    float r = fmaf(fmaf(fmaf(0.0208351f, s, -0.085133f), s, 0.180141f), s, -0.3302995f);
    r = a * fmaf(r, s, 0.9998660f);
    if (ay > ax)  r = 1.57079632679f - r;
    if (x < 0.0f) r = 3.14159265359f - r;
    return copysignf(r, y);
}

// Load 4 consecutive fp16 LDS values (8B-aligned) -> 4 floats.
__device__ __forceinline__ void load4h(const __half* p, float* dst) {
    float2 raw = *reinterpret_cast<const float2*>(p);
    __half2 a = *reinterpret_cast<__half2*>(&raw.x);
    __half2 b = *reinterpret_cast<__half2*>(&raw.y);
    float2 fa = __half22float2(a), fb = __half22float2(b);
    dst[0] = fa.x; dst[1] = fa.y; dst[2] = fb.x; dst[3] = fb.y;
}

__global__ __launch_bounds__(256, 6) void fused_kernel(const float* __restrict__ x,
                                                       float* __restrict__ out) {
    __shared__ __align__(16) __half lds[10][HTH * LPH];   // 25920 B -> 6 blocks/CU

    // XCD-contiguous swizzle: 4096 blocks % 8 XCDs == 0 -> bijective.
    int bid0 = blockIdx.x;
    int bid  = (bid0 & 7) * (NIMG * TILES_H * TILES_W / 8) + (bid0 >> 3);

    int n   = bid / (TILES_H * TILES_W);
    int t   = bid - n * (TILES_H * TILES_W);
    int th  = t / TILES_W;
    int tw  = t - th * TILES_W;
    int h0  = th * TH;
    int w0  = tw * TW;

    const float* xb = x + (size_t)n * 3 * HW;
    int tid = threadIdx.x;

    // ---- Phase A: ch0..9 over the (18 x 66) halo region into fp16 LDS ----
    for (int i = tid; i < HTH * HTW; i += 256) {
        int hr = i / HTW;
        int wc = i - hr * HTW;
        int h  = h0 + hr - 1;
        int w  = w0 + wc - 1;

        float e0 = 0.f, e1 = 0.f, m = 0.f, ang = 0.f, en0 = 0.f, en1 = 0.f;
        float cp = 0.f, dl = 0.f, smax = 0.f, smin = 0.f;

        if (h >= 0 && h < IMG_H && w >= 0 && w < IMG_W) {
            int rem = h * IMG_W + w;
            e0 = xb[rem];
            e1 = xb[HW + rem];
            dl = xb[2 * HW + rem];

            float s2 = fmaf(e0, e0, e1 * e1);
            m   = sqrt_fast(s2);
            float is = rsq_fast(s2);
            en0 = e0 * is;
            en1 = e1 * is;
            ang = 0.5f * fast_atan2f(e0, e1);
            cp  = e0 * e1;

            float dpu = 0.f, dpd = 0.f, dpl = 0.f, dpr = 0.f;
            if (h + 1 < IMG_H) {
                float a0 = xb[rem + IMG_W], a1 = xb[HW + rem + IMG_W];
                float mi = rsq_fast(fmaf(a0, a0, a1 * a1));
                dpu = fmaf(en0, a0 * mi, en1 * (a1 * mi));
            }
            if (h > 0) {
                float a0 = xb[rem - IMG_W], a1 = xb[HW + rem - IMG_W];
                float mi = rsq_fast(fmaf(a0, a0, a1 * a1));
                dpd = fmaf(en0, a0 * mi, en1 * (a1 * mi));
            }
            if (w + 1 < IMG_W) {
                float a0 = xb[rem + 1], a1 = xb[HW + rem + 1];
                float mi = rsq_fast(fmaf(a0, a0, a1 * a1));
                dpl = fmaf(en0, a0 * mi, en1 * (a1 * mi));
            }
            if (w > 0) {
                float a0 = xb[rem - 1], a1 = xb[HW + rem - 1];
                float mi = rsq_fast(fmaf(a0, a0, a1 * a1));
                dpr = fmaf(en0, a0 * mi, en1 * (a1 * mi));
            }
            smax = fmaxf(fmaxf(dpu, dpd), fmaxf(dpl, dpr));
            smin = fminf(fminf(dpu, dpd), fminf(dpl, dpr));
        }

        int li = hr * LPH + wc + PAD;
        lds[0][li] = __float2half(e0);
        lds[1][li] = __float2half(e1);
        lds[2][li] = __float2half(m);
        lds[3][li] = __float2half(ang);
        lds[4][li] = __float2half(en0);
        lds[5][li] = __float2half(en1);
        lds[6][li] = __float2half(cp);
        lds[7][li] = __float2half(dl);
        lds[8][li] = __float2half(smax);
        lds[9][li] = __float2half(smin);
    }

    __syncthreads();

    // ---- Phase B: each thread owns 4 consecutive pixels of one row ----
    int r  = tid >> 4;          // 0..15
    int c  = tid & 15;          // 0..15 -> tile cols 4c..4c+3
    int h  = h0 + r;
    int wa = w0 + 4 * c;
    float* op = out + (size_t)n * 20 * HW + (size_t)h * IMG_W + wa;

    // window tile cols 4c-1 .. 4c+6 -> halo cols 4c .. 4c+7 -> LDS idx 4c+PAD ..
    int off = 4 * c + PAD;
    int rt = r * LPH + off;          // top halo row (r)
    int rm = (r + 1) * LPH + off;    // middle (r+1)
    int rb = (r + 2) * LPH + off;    // bottom (r+2)

#pragma unroll
    for (int ch = 0; ch < 10; ++ch) {
        const __half* L = lds[ch];

        float tt[8], mm[8], bb[8];
        load4h(&L[rt], tt); load4h(&L[rt + 4], tt + 4);
        load4h(&L[rm], mm); load4h(&L[rm + 4], mm + 4);
        load4h(&L[rb], bb); load4h(&L[rb + 4], bb + 4);

        float vs[6], dd[6];
#pragma unroll
        for (int j = 0; j < 6; ++j) {
            vs[j] = tt[j] + fmaf(2.0f, mm[j], bb[j]);   // vertical [1,2,1] for gx
            dd[j] = bb[j] - tt[j];                       // vertical [-1,0,1] for gy
        }

        vfloat4 mag;
        float gx, gy;
        gx = vs[2] - vs[0]; gy = fmaf(2.0f, dd[1], dd[0] + dd[2]);
        mag.x = sqrt_fast(fmaf(gx, gx, gy * gy));
        gx = vs[3] - vs[1]; gy = fmaf(2.0f, dd[2], dd[1] + dd[3]);
        mag.y = sqrt_fast(fmaf(gx, gx, gy * gy));
        gx = vs[4] - vs[2]; gy = fmaf(2.0f, dd[3], dd[2] + dd[4]);
        mag.z = sqrt_fast(fmaf(gx, gx, gy * gy));
        gx = vs[5] - vs[3]; gy = fmaf(2.0f, dd[4], dd[3] + dd[5]);
        mag.w = sqrt_fast(fmaf(gx, gx, gy * gy));

        vfloat4 cen;
        cen.x = mm[1]; cen.y = mm[2]; cen.z = mm[3]; cen.w = mm[4];

        __builtin_nontemporal_store(cen, reinterpret_cast<vfloat4*>(&op[(size_t)ch * HW]));
        __builtin_nontemporal_store(mag, reinterpret_cast<vfloat4*>(&op[(size_t)(10 + ch) * HW]));
    }
}

extern "C" void kernel_launch(void* const* d_in, const int* in_sizes, int n_in,
                              void* d_out, int out_size, void* d_ws, size_t ws_size,
                              hipStream_t stream) {
    const float* x = (const float*)d_in[0];
    float* out = (float*)d_out;

    int grid = NIMG * TILES_H * TILES_W;   // 4096
    fused_kernel<<<grid, 256, 0, stream>>>(x, out);
}

// Round 6
// 70.410 us; speedup vs baseline: 2.8798x; 1.0612x over previous
//
#include <hip/hip_runtime.h>
#include <hip/hip_fp16.h>
#include <math.h>

#define IMG_H 512
#define IMG_W 512
#define NIMG  16
#define HW    (IMG_H * IMG_W)

#define TH 16
#define TW 64
#define HTH (TH + 2)          // 18 halo rows (channel planes)
#define HTW (TW + 2)          // 66 halo cols
#define ERH (TH + 4)          // 20 en-ring rows
#define ERW (TW + 4)          // 68 en-ring cols
#define LPH 72                // halves stride, channel planes (144 B)
#define PAD 4                 // left pad (halves): b64 reads 8B-aligned
#define EPS 72                // half2 stride, en plane (288 B)
#define PADE 3                // left pad (half2): b128 window reads 16B-aligned
#define TILES_H (IMG_H / TH)  // 32
#define TILES_W (IMG_W / TW)  // 8

typedef float vfloat4 __attribute__((ext_vector_type(4)));

__device__ __forceinline__ float rcp_fast(float v) {
#if __has_builtin(__builtin_amdgcn_rcpf)
    return __builtin_amdgcn_rcpf(v);
#else
    return 1.0f / v;
#endif
}
__device__ __forceinline__ float rsq_fast(float v) {
#if __has_builtin(__builtin_amdgcn_rsqf)
    return __builtin_amdgcn_rsqf(v);
#else
    return rsqrtf(v);
#endif
}
__device__ __forceinline__ float sqrt_fast(float v) {
#if __has_builtin(__builtin_amdgcn_sqrtf)
    return __builtin_amdgcn_sqrtf(v);
#else
    return sqrtf(v);
#endif
}

// atan2 via polynomial; |err| ~1e-4 rad (abs threshold is 0.66).
__device__ __forceinline__ float fast_atan2f(float y, float x) {
    float ay = fabsf(y), ax = fabsf(x);
    float mx = fmaxf(ay, ax), mn = fminf(ay, ax);
    float a = mn * rcp_fast(mx);
    float s = a * a;
    float r = fmaf(fmaf(fmaf(0.0208351f, s, -0.085133f), s, 0.180141f), s, -0.3302995f);
    r = a * fmaf(r, s, 0.9998660f);
    if (ay > ax)  r = 1.57079632679f - r;
    if (x < 0.0f) r = 3.14159265359f - r;
    return copysignf(r, y);
}

// Load 4 consecutive fp16 LDS values (8B-aligned) -> 4 floats.
__device__ __forceinline__ void load4h(const __half* p, float* dst) {
    float2 raw = *reinterpret_cast<const float2*>(p);
    __half2 a = *reinterpret_cast<__half2*>(&raw.x);
    __half2 b = *reinterpret_cast<__half2*>(&raw.y);
    float2 fa = __half22float2(a), fb = __half22float2(b);
    dst[0] = fa.x; dst[1] = fa.y; dst[2] = fb.x; dst[3] = fb.y;
}

// Load 8 consecutive half2 (16B-aligned) -> 8 en0 floats + 8 en1 floats.
__device__ __forceinline__ void loadrow8(const __half2* p, float* a, float* b) {
    union { vfloat4 v; __half2 h[4]; } u0, u1;
    u0.v = *reinterpret_cast<const vfloat4*>(p);
    u1.v = *reinterpret_cast<const vfloat4*>(p + 4);
#pragma unroll
    for (int j = 0; j < 4; ++j) {
        float2 f = __half22float2(u0.h[j]);
        a[j] = f.x; b[j] = f.y;
    }
#pragma unroll
    for (int j = 0; j < 4; ++j) {
        float2 f = __half22float2(u1.h[j]);
        a[4 + j] = f.x; b[4 + j] = f.y;
    }
}

// 3x6 window (as three 6..8-wide rows) -> 4 Sobel magnitudes.
__device__ __forceinline__ vfloat4 sobel4(const float* tt, const float* mm, const float* bb) {
    float vs[6], dd[6];
#pragma unroll
    for (int j = 0; j < 6; ++j) {
        vs[j] = tt[j] + fmaf(2.0f, mm[j], bb[j]);   // vertical [1,2,1] for gx
        dd[j] = bb[j] - tt[j];                       // vertical [-1,0,1] for gy
    }
    vfloat4 mag;
    float gx, gy;
    gx = vs[2] - vs[0]; gy = fmaf(2.f, dd[1], dd[0] + dd[2]);
    mag.x = sqrt_fast(fmaf(gx, gx, gy * gy));
    gx = vs[3] - vs[1]; gy = fmaf(2.f, dd[2], dd[1] + dd[3]);
    mag.y = sqrt_fast(fmaf(gx, gx, gy * gy));
    gx = vs[4] - vs[2]; gy = fmaf(2.f, dd[3], dd[2] + dd[4]);
    mag.z = sqrt_fast(fmaf(gx, gx, gy * gy));
    gx = vs[5] - vs[3]; gy = fmaf(2.f, dd[4], dd[3] + dd[5]);
    mag.w = sqrt_fast(fmaf(gx, gx, gy * gy));
    return mag;
}

__global__ __launch_bounds__(256, 6) void fused_kernel(const float* __restrict__ x,
                                                       float* __restrict__ out) {
    // 8 channel planes (e0,e1,m,ang,cp,dl,smax,smin): 8*18*72*2 = 20736 B
    // en plane (en0,en1 interleaved, 20-row ring):     20*72*4  =  5760 B
    // total 26496 B -> exactly 6 blocks/CU.
    __shared__ __align__(16) __half  lds[8][HTH * LPH];
    __shared__ __align__(16) __half2 lden[ERH * EPS];

    // XCD-contiguous swizzle: 4096 blocks % 8 XCDs == 0 -> bijective.
    int bid0 = blockIdx.x;
    int bid  = (bid0 & 7) * (NIMG * TILES_H * TILES_W / 8) + (bid0 >> 3);

    int n   = bid / (TILES_H * TILES_W);
    int t   = bid - n * (TILES_H * TILES_W);
    int th  = t / TILES_W;
    int tw  = t - th * TILES_W;
    int h0  = th * TH;
    int w0  = tw * TW;

    const float* xb = x + (size_t)n * 3 * HW;
    int tid = threadIdx.x;

    // ---- A1: en over the 20x68 ring; per-pixel channels over 18x66 ----
    for (int i = tid; i < ERH * ERW; i += 256) {
        int er = i / ERW;
        int ec = i - er * ERW;
        int h  = h0 + er - 2;
        int w  = w0 + ec - 2;
        bool inimg = (h >= 0) && (h < IMG_H) && (w >= 0) && (w < IMG_W);
        int rem = h * IMG_W + w;

        float e0 = 0.f, e1 = 0.f, en0 = 0.f, en1 = 0.f;
        if (inimg) {
            e0 = xb[rem];
            e1 = xb[HW + rem];
            float is = rsq_fast(fmaf(e0, e0, e1 * e1));
            en0 = e0 * is;
            en1 = e1 * is;
        }
        lden[er * EPS + ec + PADE] = __floats2half2_rn(en0, en1);

        int hr = er - 1, wc = ec - 1;
        if (hr >= 0 && hr < HTH && wc >= 0 && wc < HTW) {
            float dl = 0.f, m = 0.f, ang = 0.f, cp = 0.f;
            if (inimg) {
                dl = xb[2 * HW + rem];
                float s2 = fmaf(e0, e0, e1 * e1);
                m   = sqrt_fast(s2);
                ang = 0.5f * fast_atan2f(e0, e1);
                cp  = e0 * e1;
            }
            int li = hr * LPH + wc + PAD;
            lds[0][li] = __float2half(e0);
            lds[1][li] = __float2half(e1);
            lds[2][li] = __float2half(m);
            lds[3][li] = __float2half(ang);
            lds[4][li] = __float2half(cp);
            lds[5][li] = __float2half(dl);
        }
    }
    __syncthreads();

    // ---- A2: neighbor similarity (ch8/9) purely from LDS en plane ----
    for (int i = tid; i < HTH * HTW; i += 256) {
        int hr = i / HTW;
        int wc = i - hr * HTW;
        int eb = (hr + 1) * EPS + (wc + 1) + PADE;

        float2 o  = __half22float2(lden[eb]);
        float2 u  = __half22float2(lden[eb + EPS]);   // h+1
        float2 d  = __half22float2(lden[eb - EPS]);   // h-1
        float2 lf = __half22float2(lden[eb + 1]);     // w+1
        float2 rg = __half22float2(lden[eb - 1]);     // w-1

        float dpu = fmaf(o.x, u.x,  o.y * u.y);
        float dpd = fmaf(o.x, d.x,  o.y * d.y);
        float dpl = fmaf(o.x, lf.x, o.y * lf.y);
        float dpr = fmaf(o.x, rg.x, o.y * rg.y);

        float smax = fmaxf(fmaxf(dpu, dpd), fmaxf(dpl, dpr));
        float smin = fminf(fminf(dpu, dpd), fminf(dpl, dpr));

        int li = hr * LPH + wc + PAD;
        lds[6][li] = __float2half(smax);
        lds[7][li] = __float2half(smin);
    }
    __syncthreads();

    // ---- B: each thread owns 4 consecutive pixels of one row ----
    int r  = tid >> 4;          // 0..15
    int c  = tid & 15;          // 0..15 -> tile cols 4c..4c+3
    int h  = h0 + r;
    int wa = w0 + 4 * c;
    float* op = out + (size_t)n * 20 * HW + (size_t)h * IMG_W + wa;

    int off = 4 * c + PAD;
    int rt = r * LPH + off;
    int rm = (r + 1) * LPH + off;
    int rb = (r + 2) * LPH + off;

    const int outch[8] = {0, 1, 2, 3, 6, 7, 8, 9};   // plane p -> output channel

#pragma unroll
    for (int p = 0; p < 8; ++p) {
        const __half* L = lds[p];
        float tt[8], mm[8], bb[8];
        load4h(&L[rt], tt); load4h(&L[rt + 4], tt + 4);
        load4h(&L[rm], mm); load4h(&L[rm + 4], mm + 4);
        load4h(&L[rb], bb); load4h(&L[rb + 4], bb + 4);

        vfloat4 mag = sobel4(tt, mm, bb);
        vfloat4 cen;
        cen.x = mm[1]; cen.y = mm[2]; cen.z = mm[3]; cen.w = mm[4];

        int ch = outch[p];
        __builtin_nontemporal_store(cen, reinterpret_cast<vfloat4*>(&op[(size_t)ch * HW]));
        __builtin_nontemporal_store(mag, reinterpret_cast<vfloat4*>(&op[(size_t)(10 + ch) * HW]));
    }

    // ch4/ch5 (en0/en1) from the interleaved en plane; window rows er = r+1..r+3,
    // cols ec = 4c+1 .. 4c+8 -> idx er*EPS + 4c+4 (16B-aligned for b128).
    {
        int eb0 = (r + 1) * EPS + 4 * c + 4;
        float ta[8], tb[8], ma[8], mb[8], ba[8], bb2[8];
        loadrow8(&lden[eb0],            ta, tb);
        loadrow8(&lden[eb0 + EPS],      ma, mb);
        loadrow8(&lden[eb0 + 2 * EPS],  ba, bb2);

        vfloat4 mag4 = sobel4(ta, ma, ba);
        vfloat4 mag5 = sobel4(tb, mb, bb2);
        vfloat4 cen4, cen5;
        cen4.x = ma[1]; cen4.y = ma[2]; cen4.z = ma[3]; cen4.w = ma[4];
        cen5.x = mb[1]; cen5.y = mb[2]; cen5.z = mb[3]; cen5.w = mb[4];

        __builtin_nontemporal_store(cen4, reinterpret_cast<vfloat4*>(&op[(size_t)4 * HW]));
        __builtin_nontemporal_store(mag4, reinterpret_cast<vfloat4*>(&op[(size_t)14 * HW]));
        __builtin_nontemporal_store(cen5, reinterpret_cast<vfloat4*>(&op[(size_t)5 * HW]));
        __builtin_nontemporal_store(mag5, reinterpret_cast<vfloat4*>(&op[(size_t)15 * HW]));
    }
}

extern "C" void kernel_launch(void* const* d_in, const int* in_sizes, int n_in,
                              void* d_out, int out_size, void* d_ws, size_t ws_size,
                              hipStream_t stream) {
    const float* x = (const float*)d_in[0];
    float* out = (float*)d_out;

    int grid = NIMG * TILES_H * TILES_W;   // 4096
    fused_kernel<<<grid, 256, 0, stream>>>(x, out);
}

// Round 7
// 70.226 us; speedup vs baseline: 2.8873x; 1.0026x over previous
//
#include <hip/hip_runtime.h>
#include <hip/hip_fp16.h>
#include <math.h>

#define IMG_H 512
#define IMG_W 512
#define NIMG  16
#define HW    (IMG_H * IMG_W)

#define TH 16
#define TW 64
#define HTH (TH + 2)          // 18 halo rows (pair planes)
#define HTW (TW + 2)          // 66 halo cols
#define ERH (TH + 4)          // 20 en-ring rows
#define ERW (TW + 4)          // 68 en-ring cols
#define SP  72                // stride (half2 units) for ALL planes; 288 B/row
#define PADP 4                // left pad (half2 units) -> b128 bases 16B-aligned
#define TILES_H (IMG_H / TH)  // 32
#define TILES_W (IMG_W / TW)  // 8

typedef float vfloat4 __attribute__((ext_vector_type(4)));

__device__ __forceinline__ float rcp_fast(float v) {
#if __has_builtin(__builtin_amdgcn_rcpf)
    return __builtin_amdgcn_rcpf(v);
#else
    return 1.0f / v;
#endif
}
__device__ __forceinline__ float rsq_fast(float v) {
#if __has_builtin(__builtin_amdgcn_rsqf)
    return __builtin_amdgcn_rsqf(v);
#else
    return rsqrtf(v);
#endif
}
__device__ __forceinline__ float sqrt_fast(float v) {
#if __has_builtin(__builtin_amdgcn_sqrtf)
    return __builtin_amdgcn_sqrtf(v);
#else
    return sqrtf(v);
#endif
}

// atan2 via polynomial; |err| ~1e-4 rad (abs threshold is 0.66).
__device__ __forceinline__ float fast_atan2f(float y, float x) {
    float ay = fabsf(y), ax = fabsf(x);
    float mx = fmaxf(ay, ax), mn = fminf(ay, ax);
    float a = mn * rcp_fast(mx);
    float s = a * a;
    float r = fmaf(fmaf(fmaf(0.0208351f, s, -0.085133f), s, 0.180141f), s, -0.3302995f);
    r = a * fmaf(r, s, 0.9998660f);
    if (ay > ax)  r = 1.57079632679f - r;
    if (x < 0.0f) r = 3.14159265359f - r;
    return copysignf(r, y);
}

// Load 8 consecutive half2 (16B-aligned) -> 8 "x" floats and 8 "y" floats.
__device__ __forceinline__ void loadrow8(const __half2* p, float* a, float* b) {
    union { vfloat4 v; __half2 h[4]; } u0, u1;
    u0.v = *reinterpret_cast<const vfloat4*>(p);
    u1.v = *reinterpret_cast<const vfloat4*>(p + 4);
#pragma unroll
    for (int j = 0; j < 4; ++j) {
        float2 f = __half22float2(u0.h[j]);
        a[j] = f.x; b[j] = f.y;
    }
#pragma unroll
    for (int j = 0; j < 4; ++j) {
        float2 f = __half22float2(u1.h[j]);
        a[4 + j] = f.x; b[4 + j] = f.y;
    }
}

// 6-wide rows -> 4 Sobel magnitudes.
__device__ __forceinline__ vfloat4 sobel4(const float* tt, const float* mm, const float* bb) {
    float vs[6], dd[6];
#pragma unroll
    for (int j = 0; j < 6; ++j) {
        vs[j] = tt[j] + fmaf(2.0f, mm[j], bb[j]);   // vertical [1,2,1] for gx
        dd[j] = bb[j] - tt[j];                       // vertical [-1,0,1] for gy
    }
    vfloat4 mag;
    float gx, gy;
    gx = vs[2] - vs[0]; gy = fmaf(2.f, dd[1], dd[0] + dd[2]);
    mag.x = sqrt_fast(fmaf(gx, gx, gy * gy));
    gx = vs[3] - vs[1]; gy = fmaf(2.f, dd[2], dd[1] + dd[3]);
    mag.y = sqrt_fast(fmaf(gx, gx, gy * gy));
    gx = vs[4] - vs[2]; gy = fmaf(2.f, dd[3], dd[2] + dd[4]);
    mag.z = sqrt_fast(fmaf(gx, gx, gy * gy));
    gx = vs[5] - vs[3]; gy = fmaf(2.f, dd[4], dd[3] + dd[5]);
    mag.w = sqrt_fast(fmaf(gx, gx, gy * gy));
    return mag;
}

__device__ __forceinline__ vfloat4 mk4(const float* m) {
    vfloat4 v; v.x = m[1]; v.y = m[2]; v.z = m[3]; v.w = m[4]; return v;
}

__global__ __launch_bounds__(256, 7) void fused_kernel(const float* __restrict__ x,
                                                       float* __restrict__ out) {
    // All planes interleaved half2, stride 72 half2 (288 B):
    //   lden: {en0,en1} on 20x68 ring  = 20*72*4 = 5760 B
    //   pe:   {e0,e1}   on 18x66 halo  = 18*72*4 = 5184 B
    //   pad2: {ang,dl}                 = 5184 B
    //   psm:  {smax,smin}              = 5184 B      total 21312 B -> 7 blocks/CU
    __shared__ __align__(16) __half2 lden[ERH * SP];
    __shared__ __align__(16) __half2 pe  [HTH * SP];
    __shared__ __align__(16) __half2 pad2[HTH * SP];
    __shared__ __align__(16) __half2 psm [HTH * SP];

    // XCD-contiguous swizzle: 4096 blocks % 8 XCDs == 0 -> bijective.
    int bid0 = blockIdx.x;
    int bid  = (bid0 & 7) * (NIMG * TILES_H * TILES_W / 8) + (bid0 >> 3);

    int n   = bid / (TILES_H * TILES_W);
    int t   = bid - n * (TILES_H * TILES_W);
    int th  = t / TILES_W;
    int tw  = t - th * TILES_W;
    int h0  = th * TH;
    int w0  = tw * TW;

    const float* xb = x + (size_t)n * 3 * HW;
    int tid = threadIdx.x;

    // ---- A1: en over the 20x68 ring; e/ang/dl planes over 18x66 ----
    for (int i = tid; i < ERH * ERW; i += 256) {
        int er = i / ERW;
        int ec = i - er * ERW;
        int h  = h0 + er - 2;
        int w  = w0 + ec - 2;
        bool inimg = (h >= 0) && (h < IMG_H) && (w >= 0) && (w < IMG_W);
        int rem = h * IMG_W + w;

        float e0 = 0.f, e1 = 0.f, en0 = 0.f, en1 = 0.f;
        if (inimg) {
            e0 = xb[rem];
            e1 = xb[HW + rem];
            float is = rsq_fast(fmaf(e0, e0, e1 * e1));
            en0 = e0 * is;
            en1 = e1 * is;
        }
        lden[er * SP + ec + PADP] = __floats2half2_rn(en0, en1);

        int hr = er - 1, wc = ec - 1;
        if (hr >= 0 && hr < HTH && wc >= 0 && wc < HTW) {
            float dl = 0.f, ang = 0.f;
            if (inimg) {
                dl  = xb[2 * HW + rem];
                ang = 0.5f * fast_atan2f(e0, e1);
            }
            pe  [hr * SP + wc + PADP] = __floats2half2_rn(e0, e1);
            pad2[hr * SP + wc + PADP] = __floats2half2_rn(ang, dl);
        }
    }
    __syncthreads();

    // ---- A2: neighbor similarity (smax/smin) from the en plane ----
    for (int i = tid; i < HTH * HTW; i += 256) {
        int hr = i / HTW;
        int wc = i - hr * HTW;
        int eb = (hr + 1) * SP + (wc + 1) + PADP;

        float2 o  = __half22float2(lden[eb]);
        float2 u  = __half22float2(lden[eb + SP]);   // h+1
        float2 d  = __half22float2(lden[eb - SP]);   // h-1
        float2 lf = __half22float2(lden[eb + 1]);    // w+1
        float2 rg = __half22float2(lden[eb - 1]);    // w-1

        float dpu = fmaf(o.x, u.x,  o.y * u.y);
        float dpd = fmaf(o.x, d.x,  o.y * d.y);
        float dpl = fmaf(o.x, lf.x, o.y * lf.y);
        float dpr = fmaf(o.x, rg.x, o.y * rg.y);

        float smax = fmaxf(fmaxf(dpu, dpd), fmaxf(dpl, dpr));
        float smin = fminf(fminf(dpu, dpd), fminf(dpl, dpr));

        psm[hr * SP + wc + PADP] = __floats2half2_rn(smax, smin);
    }
    __syncthreads();

    // ---- B: each thread owns 4 consecutive pixels of one row ----
    int r  = tid >> 4;          // 0..15
    int c  = tid & 15;          // 0..15 -> tile cols 4c..4c+3
    int h  = h0 + r;
    int wa = w0 + 4 * c;
    float* op = out + (size_t)n * 20 * HW + (size_t)h * IMG_W + wa;

    int pb = r * SP + 4 * c + PADP;         // top window row, pair planes
    int ebn = (r + 1) * SP + 4 * c + PADP;  // top window row, en plane

#define NTST(CH, V) __builtin_nontemporal_store((V), reinterpret_cast<vfloat4*>(&op[(size_t)(CH) * HW]))

    // -- {e0,e1} group: ch0,1 (+10,11) and derived m (ch2,12), cp (ch6,16) --
    {
        float ta[8], tb[8], ma[8], mb[8], ba[8], bb[8];
        loadrow8(&pe[pb],          ta, tb);
        loadrow8(&pe[pb + SP],     ma, mb);
        loadrow8(&pe[pb + 2 * SP], ba, bb);

        NTST(0, mk4(ma));  NTST(10, sobel4(ta, ma, ba));
        NTST(1, mk4(mb));  NTST(11, sobel4(tb, mb, bb));

        float tm[6], mm_[6], bm[6];
#pragma unroll
        for (int j = 0; j < 6; ++j) {
            tm[j]  = sqrt_fast(fmaf(ta[j], ta[j], tb[j] * tb[j]));
            mm_[j] = sqrt_fast(fmaf(ma[j], ma[j], mb[j] * mb[j]));
            bm[j]  = sqrt_fast(fmaf(ba[j], ba[j], bb[j] * bb[j]));
        }
        NTST(2, mk4(mm_)); NTST(12, sobel4(tm, mm_, bm));

        float tc[6], mc[6], bc[6];
#pragma unroll
        for (int j = 0; j < 6; ++j) {
            tc[j] = ta[j] * tb[j];
            mc[j] = ma[j] * mb[j];
            bc[j] = ba[j] * bb[j];
        }
        NTST(6, mk4(mc));  NTST(16, sobel4(tc, mc, bc));
    }

    // -- {ang,dl} group: ch3,7 (+13,17) --
    {
        float ta[8], tb[8], ma[8], mb[8], ba[8], bb[8];
        loadrow8(&pad2[pb],          ta, tb);
        loadrow8(&pad2[pb + SP],     ma, mb);
        loadrow8(&pad2[pb + 2 * SP], ba, bb);

        NTST(3, mk4(ma));  NTST(13, sobel4(ta, ma, ba));
        NTST(7, mk4(mb));  NTST(17, sobel4(tb, mb, bb));
    }

    // -- {smax,smin} group: ch8,9 (+18,19) --
    {
        float ta[8], tb[8], ma[8], mb[8], ba[8], bb[8];
        loadrow8(&psm[pb],          ta, tb);
        loadrow8(&psm[pb + SP],     ma, mb);
        loadrow8(&psm[pb + 2 * SP], ba, bb);

        NTST(8, mk4(ma));  NTST(18, sobel4(ta, ma, ba));
        NTST(9, mk4(mb));  NTST(19, sobel4(tb, mb, bb));
    }

    // -- {en0,en1} group: ch4,5 (+14,15); window shifted +1 within the ring --
    {
        float ta[8], tb[8], ma[8], mb[8], ba[8], bb[8];
        loadrow8(&lden[ebn],          ta, tb);
        loadrow8(&lden[ebn + SP],     ma, mb);
        loadrow8(&lden[ebn + 2 * SP], ba, bb);

        vfloat4 c4, c5;
        c4.x = ma[2]; c4.y = ma[3]; c4.z = ma[4]; c4.w = ma[5];
        c5.x = mb[2]; c5.y = mb[3]; c5.z = mb[4]; c5.w = mb[5];
        NTST(4, c4);  NTST(14, sobel4(ta + 1, ma + 1, ba + 1));
        NTST(5, c5);  NTST(15, sobel4(tb + 1, mb + 1, bb + 1));
    }
#undef NTST
}

extern "C" void kernel_launch(void* const* d_in, const int* in_sizes, int n_in,
                              void* d_out, int out_size, void* d_ws, size_t ws_size,
                              hipStream_t stream) {
    const float* x = (const float*)d_in[0];
    float* out = (float*)d_out;

    int grid = NIMG * TILES_H * TILES_W;   // 4096
    fused_kernel<<<grid, 256, 0, stream>>>(x, out);
}